// Round 1
// baseline (134.486 us; speedup 1.0000x reference)
//
#include <hip/hip_runtime.h>

#define IN_DIM  4096
#define OUT_DIM 11008
#define NSUB    1376
#define KSQ     256
#define DSUB    8
#define BATCH   32

#define DTILE   16                   // subspaces per block -> N tile = 128
#define NTILE   128
#define KC      128                  // k elements staged per chunk
#define KSPLIT  8                    // k-blocks in grid
#define KPB     (IN_DIM / KSPLIT)    // 512 k per block
#define NCHUNK  (KPB / KC)           // 4 chunks per block
#define NBLK    (OUT_DIM / NTILE)    // 86

typedef __attribute__((ext_vector_type(8))) short bf16x8;
typedef __attribute__((ext_vector_type(4))) float f32x4;

// LDS row strides (elements). 136 bf16 = 68 dwords -> stride % 32 banks == 4,
// spreads the 16-lane frag reads (64-dword stride would be 16-way conflicted).
#define SW_STRIDE 136
#define SX_STRIDE 136
#define SI_STRIDE 132

__device__ __forceinline__ unsigned short f2bf(float f) {
    union { float f; unsigned u; } a; a.f = f;
    unsigned u = a.u;
    u += 0x7fffu + ((u >> 16) & 1u);   // round-to-nearest-even
    return (unsigned short)(u >> 16);
}

__global__ __launch_bounds__(256) void pq_main(
    const float* __restrict__ x, const float* __restrict__ vecs,
    const int* __restrict__ idx, float* __restrict__ part)
{
    __shared__ unsigned short sW[NTILE * SW_STRIDE];  // W^T tile [n][k], bf16
    __shared__ unsigned short sX[BATCH * SX_STRIDE];  // x tile [m][k], bf16
    __shared__ int            sI[DTILE * SI_STRIDE];  // idx tile [d][i]

    const int t    = threadIdx.x;
    const int nblk = blockIdx.x;        // 0..85
    const int kblk = blockIdx.y;        // 0..7
    const int d0   = nblk * DTILE;
    const int kbase = kblk * KPB;

    const int wave = t >> 6;
    const int lane = t & 63;
    const int l15  = lane & 15;
    const int l4   = lane >> 4;

    const int gd = t >> 4;              // gather: subspace 0..15
    const int go = t & 15;              // gather: k-oct 0..15

    f32x4 acc[2][2];
    #pragma unroll
    for (int i = 0; i < 2; ++i)
        #pragma unroll
        for (int j = 0; j < 2; ++j)
            acc[i][j] = (f32x4)0.0f;

    for (int c = 0; c < NCHUNK; ++c) {
        const int i0 = kbase + c * KC;
        __syncthreads();   // previous chunk's frag reads done before restaging

        // --- stage indexes, transposed to [d][i] (coalesced 64B-per-row reads)
        #pragma unroll
        for (int p = 0; p < 8; ++p) {
            int flat = p * 256 + t;                 // 0..2047
            int ii = flat >> 4, dd = flat & 15;
            sI[dd * SI_STRIDE + ii] = idx[(size_t)(i0 + ii) * NSUB + (d0 + dd)];
        }
        // --- stage x chunk, fp32 -> bf16
        #pragma unroll
        for (int p = 0; p < 4; ++p) {
            int flat = p * 256 + t;                 // float4 chunk 0..1023
            int b = flat >> 5, iq = flat & 31;
            float4 v = *(const float4*)&x[(size_t)b * IN_DIM + i0 + iq * 4];
            uint2 pk;
            pk.x = f2bf(v.x) | ((unsigned)f2bf(v.y) << 16);
            pk.y = f2bf(v.z) | ((unsigned)f2bf(v.w) << 16);
            *(uint2*)&sX[b * SX_STRIDE + iq * 4] = pk;
        }
        __syncthreads();

        // --- gather 8 codewords (8 consecutive k, one d) per thread,
        //     transpose 8x8 in registers, write k-contiguous b128s into sW[n][k]
        int kk[8];
        #pragma unroll
        for (int s = 0; s < 8; ++s)
            kk[s] = sI[gd * SI_STRIDE + go * 8 + s];

        unsigned short cw[8][8];                    // [k-sub][j]
        #pragma unroll
        for (int s = 0; s < 8; ++s) {
            const float4* src =
                (const float4*)&vecs[((size_t)(d0 + gd) * KSQ + kk[s]) * DSUB];
            float4 aa = src[0];
            float4 bb = src[1];
            cw[s][0] = f2bf(aa.x); cw[s][1] = f2bf(aa.y);
            cw[s][2] = f2bf(aa.z); cw[s][3] = f2bf(aa.w);
            cw[s][4] = f2bf(bb.x); cw[s][5] = f2bf(bb.y);
            cw[s][6] = f2bf(bb.z); cw[s][7] = f2bf(bb.w);
        }
        #pragma unroll
        for (int j = 0; j < 8; ++j) {
            uint4 wv;
            wv.x = cw[0][j] | ((unsigned)cw[1][j] << 16);
            wv.y = cw[2][j] | ((unsigned)cw[3][j] << 16);
            wv.z = cw[4][j] | ((unsigned)cw[5][j] << 16);
            wv.w = cw[6][j] | ((unsigned)cw[7][j] << 16);
            *(uint4*)&sW[(gd * 8 + j) * SW_STRIDE + go * 8] = wv;
        }
        __syncthreads();

        // --- MFMA over this chunk: wave owns 32 cols, full M=32
        #pragma unroll
        for (int kq = 0; kq < KC / 32; ++kq) {
            bf16x8 A[2], B[2];
            #pragma unroll
            for (int mt = 0; mt < 2; ++mt)
                A[mt] = *(const bf16x8*)
                    &sX[(mt * 16 + l15) * SX_STRIDE + kq * 32 + l4 * 8];
            #pragma unroll
            for (int nt = 0; nt < 2; ++nt)
                B[nt] = *(const bf16x8*)
                    &sW[(wave * 32 + nt * 16 + l15) * SW_STRIDE + kq * 32 + l4 * 8];
            #pragma unroll
            for (int mt = 0; mt < 2; ++mt)
                #pragma unroll
                for (int nt = 0; nt < 2; ++nt)
                    acc[mt][nt] = __builtin_amdgcn_mfma_f32_16x16x32_bf16(
                        A[mt], B[nt], acc[mt][nt], 0, 0, 0);
        }
    }

    // --- epilogue: write fp32 partial tile for this k-block
    float* pout = part + (size_t)kblk * (BATCH * OUT_DIM);
    #pragma unroll
    for (int mt = 0; mt < 2; ++mt)
        #pragma unroll
        for (int nt = 0; nt < 2; ++nt)
            #pragma unroll
            for (int r = 0; r < 4; ++r) {
                int row = mt * 16 + l4 * 4 + r;                       // batch
                int col = nblk * NTILE + wave * 32 + nt * 16 + l15;   // out col
                pout[(size_t)row * OUT_DIM + col] = acc[mt][nt][r];
            }
}

__global__ __launch_bounds__(256) void pq_reduce(
    const float* __restrict__ part, const float* __restrict__ bias,
    float* __restrict__ out)
{
    int e = blockIdx.x * 256 + threadIdx.x;     // 352256 = 1376*256 exactly
    int col = e % OUT_DIM;
    float s = bias[col];
    #pragma unroll
    for (int k = 0; k < KSPLIT; ++k)
        s += part[(size_t)k * (BATCH * OUT_DIM) + e];
    out[e] = s;
}

extern "C" void kernel_launch(void* const* d_in, const int* in_sizes, int n_in,
                              void* d_out, int out_size, void* d_ws, size_t ws_size,
                              hipStream_t stream) {
    const float* x    = (const float*)d_in[0];
    const float* vecs = (const float*)d_in[1];
    const float* bias = (const float*)d_in[2];
    const int*   idx  = (const int*)d_in[3];
    float* out  = (float*)d_out;
    float* part = (float*)d_ws;    // KSPLIT * 32 * 11008 fp32 = 11.3 MB

    dim3 grid(NBLK, KSPLIT);
    pq_main<<<grid, 256, 0, stream>>>(x, vecs, idx, part);
    pq_reduce<<<BATCH * OUT_DIM / 256, 256, 0, stream>>>(part, bias, out);
}

// Round 2
// 115.404 us; speedup vs baseline: 1.1653x; 1.1653x over previous
//
#include <hip/hip_runtime.h>

#define IN_DIM  4096
#define OUT_DIM 11008
#define NSUB    1376
#define KSQ     256
#define DSUB    8
#define BATCH   32

#define DTILE   16                   // subspaces per block -> N tile = 128
#define NTILE   128
#define KC      128                  // k elements staged per chunk
#define KSPLIT  16                   // k-blocks in grid
#define KPB     (IN_DIM / KSPLIT)    // 256 k per block
#define NCHUNK  (KPB / KC)           // 2 chunks per block
#define NBLK    (OUT_DIM / NTILE)    // 86

typedef unsigned short ushort_t;
typedef unsigned int   uint_t;
typedef __attribute__((ext_vector_type(8))) short bf16x8;
typedef __attribute__((ext_vector_type(4))) float f32x4;

// LDS strides (elements). 136 = 68 dwords (≡4 mod 32 banks): balanced b128 access.
#define SW_STRIDE 136
#define SX_STRIDE 136
#define SI_STRIDE 132

// workspace layout
#define VEC_N   (NSUB * KSQ * DSUB)          // 2818048 floats
#define XBF_OFF 5636096                      // bytes: VEC_N * 2
#define PREP_V  (VEC_N / 2)                  // 1409024 uint (2 bf16 each)
#define PREP_X  (BATCH * IN_DIM / 2)         // 65536
#define PREP_O  (BATCH * OUT_DIM)            // 352256
#define PREP_N  (PREP_V + PREP_X + PREP_O)   // 1826816 = 7136 * 256

__device__ __forceinline__ ushort_t f2bf(float f) {
    union { float f; uint_t u; } a; a.f = f;
    uint_t u = a.u;
    u += 0x7fffu + ((u >> 16) & 1u);   // round-to-nearest-even
    return (ushort_t)(u >> 16);
}

__global__ __launch_bounds__(256) void pq_prep(
    const float* __restrict__ x, const float* __restrict__ vecs,
    const float* __restrict__ bias,
    uint_t* __restrict__ vbf, uint_t* __restrict__ xbf, float* __restrict__ out)
{
    int tid = blockIdx.x * 256 + threadIdx.x;
    if (tid < PREP_V) {
        float2 v = ((const float2*)vecs)[tid];
        vbf[tid] = (uint_t)f2bf(v.x) | ((uint_t)f2bf(v.y) << 16);
    } else if (tid < PREP_V + PREP_X) {
        int i = tid - PREP_V;
        float2 v = ((const float2*)x)[i];
        xbf[i] = (uint_t)f2bf(v.x) | ((uint_t)f2bf(v.y) << 16);
    } else {
        int i = tid - (PREP_V + PREP_X);
        out[i] = bias[i % OUT_DIM];
    }
}

__global__ __launch_bounds__(256) void pq_main(
    const ushort_t* __restrict__ xbf, const uint4* __restrict__ vbf,
    const int* __restrict__ idx, float* __restrict__ out)
{
    __shared__ ushort_t sW[NTILE * SW_STRIDE];  // W^T tile [n][k], bf16
    __shared__ ushort_t sX[BATCH * SX_STRIDE];  // x tile [m][k], bf16
    __shared__ int      sI[DTILE * SI_STRIDE];  // idx tile [d][i]

    const int t    = threadIdx.x;
    const int nblk = blockIdx.x;        // 0..85
    const int kblk = blockIdx.y;        // 0..15
    const int d0   = nblk * DTILE;
    const int kbase = kblk * KPB;

    const int wave = t >> 6;
    const int lane = t & 63;
    const int l15  = lane & 15;
    const int l4   = lane >> 4;

    const int gd = t >> 4;              // gather: subspace 0..15
    const int go = t & 15;              // gather: k-oct 0..15

    f32x4 acc[2][2];
    #pragma unroll
    for (int i = 0; i < 2; ++i)
        #pragma unroll
        for (int j = 0; j < 2; ++j)
            acc[i][j] = (f32x4)0.0f;

    int   ireg[8];
    uint4 xreg[2];

    // prologue: prefetch chunk 0's idx + x into registers (coalesced)
    {
        const int i0 = kbase;
        #pragma unroll
        for (int p = 0; p < 8; ++p) {
            int f = p * 256 + t, ii = f >> 4, dd = f & 15;
            ireg[p] = idx[(size_t)(i0 + ii) * NSUB + (d0 + dd)];
        }
        #pragma unroll
        for (int p = 0; p < 2; ++p) {
            int f = p * 256 + t, b = f >> 4, q = f & 15;
            xreg[p] = ((const uint4*)xbf)[b * (IN_DIM / 8) + i0 / 8 + q];
        }
    }

    for (int c = 0; c < NCHUNK; ++c) {
        __syncthreads();   // previous chunk's MFMA/LDS reads done

        // --- commit prefetched regs into LDS
        #pragma unroll
        for (int p = 0; p < 8; ++p) {
            int f = p * 256 + t, ii = f >> 4, dd = f & 15;
            sI[dd * SI_STRIDE + ii] = ireg[p];
        }
        #pragma unroll
        for (int p = 0; p < 2; ++p) {
            int f = p * 256 + t, b = f >> 4, q = f & 15;
            *(uint4*)&sX[b * SX_STRIDE + q * 8] = xreg[p];
        }
        __syncthreads();

        // --- gather: 8 bf16 codewords (one uint4 each), issued first
        int kk[8];
        #pragma unroll
        for (int s = 0; s < 8; ++s)
            kk[s] = sI[gd * SI_STRIDE + go * 8 + s];

        uint4 q[8];
        #pragma unroll
        for (int s = 0; s < 8; ++s)
            q[s] = vbf[(d0 + gd) * KSQ + kk[s]];

        // --- prefetch next chunk's idx + x (HBM latency hides behind rest)
        if (c + 1 < NCHUNK) {
            const int i0n = kbase + (c + 1) * KC;
            #pragma unroll
            for (int p = 0; p < 8; ++p) {
                int f = p * 256 + t, ii = f >> 4, dd = f & 15;
                ireg[p] = idx[(size_t)(i0n + ii) * NSUB + (d0 + dd)];
            }
            #pragma unroll
            for (int p = 0; p < 2; ++p) {
                int f = p * 256 + t, b = f >> 4, qq = f & 15;
                xreg[p] = ((const uint4*)xbf)[b * (IN_DIM / 8) + i0n / 8 + qq];
            }
        }

        // --- 8x8 bf16 transpose via v_perm, write k-contiguous b128s to sW[n][k]
        #pragma unroll
        for (int j = 0; j < 8; ++j) {
            const uint_t sel = (j & 1) ? 0x07060302u : 0x05040100u;
            uint_t c0 = (j >> 1) == 0 ? q[0].x : (j >> 1) == 1 ? q[0].y : (j >> 1) == 2 ? q[0].z : q[0].w;
            uint_t c1 = (j >> 1) == 0 ? q[1].x : (j >> 1) == 1 ? q[1].y : (j >> 1) == 2 ? q[1].z : q[1].w;
            uint_t c2 = (j >> 1) == 0 ? q[2].x : (j >> 1) == 1 ? q[2].y : (j >> 1) == 2 ? q[2].z : q[2].w;
            uint_t c3 = (j >> 1) == 0 ? q[3].x : (j >> 1) == 1 ? q[3].y : (j >> 1) == 2 ? q[3].z : q[3].w;
            uint_t c4 = (j >> 1) == 0 ? q[4].x : (j >> 1) == 1 ? q[4].y : (j >> 1) == 2 ? q[4].z : q[4].w;
            uint_t c5 = (j >> 1) == 0 ? q[5].x : (j >> 1) == 1 ? q[5].y : (j >> 1) == 2 ? q[5].z : q[5].w;
            uint_t c6 = (j >> 1) == 0 ? q[6].x : (j >> 1) == 1 ? q[6].y : (j >> 1) == 2 ? q[6].z : q[6].w;
            uint_t c7 = (j >> 1) == 0 ? q[7].x : (j >> 1) == 1 ? q[7].y : (j >> 1) == 2 ? q[7].z : q[7].w;
            uint4 wv;
            wv.x = __builtin_amdgcn_perm(c1, c0, sel);
            wv.y = __builtin_amdgcn_perm(c3, c2, sel);
            wv.z = __builtin_amdgcn_perm(c5, c4, sel);
            wv.w = __builtin_amdgcn_perm(c7, c6, sel);
            *(uint4*)&sW[(gd * 8 + j) * SW_STRIDE + go * 8] = wv;
        }
        __syncthreads();

        // --- MFMA over this chunk: wave owns 32 cols, full M=32
        #pragma unroll
        for (int kq = 0; kq < KC / 32; ++kq) {
            bf16x8 A[2], B[2];
            #pragma unroll
            for (int mt = 0; mt < 2; ++mt)
                A[mt] = *(const bf16x8*)
                    &sX[(mt * 16 + l15) * SX_STRIDE + kq * 32 + l4 * 8];
            #pragma unroll
            for (int nt = 0; nt < 2; ++nt)
                B[nt] = *(const bf16x8*)
                    &sW[(wave * 32 + nt * 16 + l15) * SW_STRIDE + kq * 32 + l4 * 8];
            #pragma unroll
            for (int mt = 0; mt < 2; ++mt)
                #pragma unroll
                for (int nt = 0; nt < 2; ++nt)
                    acc[mt][nt] = __builtin_amdgcn_mfma_f32_16x16x32_bf16(
                        A[mt], B[nt], acc[mt][nt], 0, 0, 0);
        }
    }

    // --- epilogue: accumulate into out (pre-initialized with bias)
    #pragma unroll
    for (int mt = 0; mt < 2; ++mt)
        #pragma unroll
        for (int nt = 0; nt < 2; ++nt)
            #pragma unroll
            for (int r = 0; r < 4; ++r) {
                int row = mt * 16 + l4 * 4 + r;                       // batch
                int col = nblk * NTILE + wave * 32 + nt * 16 + l15;   // out col
                atomicAdd(&out[(size_t)row * OUT_DIM + col], acc[mt][nt][r]);
            }
}

extern "C" void kernel_launch(void* const* d_in, const int* in_sizes, int n_in,
                              void* d_out, int out_size, void* d_ws, size_t ws_size,
                              hipStream_t stream) {
    const float* x    = (const float*)d_in[0];
    const float* vecs = (const float*)d_in[1];
    const float* bias = (const float*)d_in[2];
    const int*   idx  = (const int*)d_in[3];
    float* out = (float*)d_out;

    uint_t* vbf = (uint_t*)d_ws;                           // 5.6 MB bf16 codebook
    uint_t* xbf = (uint_t*)((char*)d_ws + XBF_OFF);        // 256 KB bf16 x

    pq_prep<<<PREP_N / 256, 256, 0, stream>>>(x, vecs, bias, vbf, xbf, out);
    dim3 grid(NBLK, KSPLIT);
    pq_main<<<grid, 256, 0, stream>>>((const ushort_t*)xbf, (const uint4*)vbf,
                                      idx, out);
}